// Round 4
// baseline (2857.689 us; speedup 1.0000x reference)
//
#include <hip/hip_runtime.h>
#include <hip/hip_bf16.h>
#include <math.h>

#define B 2
#define S 3072
#define D 512
#define H 8
#define HD 64
#define DFF 2048
#define R 768
#define SC (S - R)
#define EPS 1e-5f

typedef __attribute__((ext_vector_type(8))) short s8v;   // 8 x bf16 bits (4 VGPR)
typedef __attribute__((ext_vector_type(4))) float f4v;   // mfma accumulator

__device__ inline short f2bf(float x) {
    __hip_bfloat16 h = __float2bfloat16(x);
    return __builtin_bit_cast(short, h);
}

// ---------------------------------------------------------------------------
// bf16-MFMA GEMM: C = A @ W^T + bias.  A: MxK row-major fp32 (row gather in
// MODE 2), W: NxK row-major fp32.  64x64 tile, 4 waves (2x2), BK=32.
// MODE 0: plain C. MODE 1: scatter to Q[b,h,s,hd]. MODE 2: scatter K/V to
// K_full/V_full at recompute_idx positions.
// ---------------------------------------------------------------------------
template<int MODE, int RELU>
__global__ __launch_bounds__(256) void gemm_mfma(
    const float* __restrict__ A, const float* __restrict__ W,
    const float* __restrict__ bias, float* __restrict__ C0,
    float* __restrict__ C1, int M, int N, int K,
    const int* __restrict__ gather_idx)
{
    __shared__ short As[64][40];   // 32 used + 8 pad (80B row, 16B aligned)
    __shared__ short Ws[64][40];
    const int t = threadIdx.x;
    const int bm = blockIdx.y * 64, bn = blockIdx.x * 64;
    const int lane = t & 63, wid = t >> 6;
    const int wm = (wid >> 1) * 32, wn = (wid & 1) * 32;  // wave sub-tile
    const int lr = lane & 15, lk = lane >> 4;             // frag row/col, k-group

    // staging: thread t loads row srow, 8 fp32 at scol, converts to bf16
    const int srow = t >> 2;
    const int scol = (t & 3) * 8;
    long arow_g;
    if (MODE == 2) {
        int r = bm + srow; int b = r / R, i = r - b * R;
        arow_g = (long)b * S + gather_idx[i];
    } else {
        arow_g = bm + srow;
    }
    const float* Ap = A + arow_g * (long)K + scol;
    const float* Wp = W + (long)(bn + srow) * K + scol;

    f4v acc[2][2] = {};

    for (int k0 = 0; k0 < K; k0 += 32) {
        float4 a0 = *(const float4*)(Ap + k0);
        float4 a1 = *(const float4*)(Ap + k0 + 4);
        float4 w0 = *(const float4*)(Wp + k0);
        float4 w1 = *(const float4*)(Wp + k0 + 4);
        __syncthreads();   // previous tile fully consumed
        s8v av, wv;
        av[0] = f2bf(a0.x); av[1] = f2bf(a0.y); av[2] = f2bf(a0.z); av[3] = f2bf(a0.w);
        av[4] = f2bf(a1.x); av[5] = f2bf(a1.y); av[6] = f2bf(a1.z); av[7] = f2bf(a1.w);
        wv[0] = f2bf(w0.x); wv[1] = f2bf(w0.y); wv[2] = f2bf(w0.z); wv[3] = f2bf(w0.w);
        wv[4] = f2bf(w1.x); wv[5] = f2bf(w1.y); wv[6] = f2bf(w1.z); wv[7] = f2bf(w1.w);
        *(s8v*)&As[srow][scol] = av;
        *(s8v*)&Ws[srow][scol] = wv;
        __syncthreads();
        // fragments: row/col = lr, k = lk*8 .. +8 (contiguous bf16x8)
        s8v af0 = *(const s8v*)&As[wm + lr][lk * 8];
        s8v af1 = *(const s8v*)&As[wm + 16 + lr][lk * 8];
        s8v bf0 = *(const s8v*)&Ws[wn + lr][lk * 8];
        s8v bf1 = *(const s8v*)&Ws[wn + 16 + lr][lk * 8];
        acc[0][0] = __builtin_amdgcn_mfma_f32_16x16x32_bf16(af0, bf0, acc[0][0], 0, 0, 0);
        acc[0][1] = __builtin_amdgcn_mfma_f32_16x16x32_bf16(af0, bf1, acc[0][1], 0, 0, 0);
        acc[1][0] = __builtin_amdgcn_mfma_f32_16x16x32_bf16(af1, bf0, acc[1][0], 0, 0, 0);
        acc[1][1] = __builtin_amdgcn_mfma_f32_16x16x32_bf16(af1, bf1, acc[1][1], 0, 0, 0);
    }

    // epilogue: C/D layout col=lane&15, row=(lane>>4)*4+reg (m89-verified)
#pragma unroll
    for (int mi = 0; mi < 2; mi++) {
#pragma unroll
        for (int ni = 0; ni < 2; ni++) {
#pragma unroll
            for (int i = 0; i < 4; i++) {
                int m = bm + wm + mi * 16 + lk * 4 + i;
                int n = bn + wn + ni * 16 + lr;
                float v = acc[mi][ni][i] + bias[n];
                if (RELU) v = fmaxf(v, 0.f);
                if (MODE == 0) {
                    C0[(long)m * N + n] = v;
                } else if (MODE == 1) {     // Q scatter: (b,s) x (h,hd)
                    int b = m / S, s = m - b * S;
                    int h = n >> 6, hd = n & 63;
                    C0[(((long)(b * H + h)) * S + s) * HD + hd] = v;
                } else {                    // KV scatter at recompute positions
                    int b = m / R, i2 = m - b * R;
                    int s = gather_idx[i2];
                    int c = n;
                    float* dst = C0;
                    if (c >= D) { c -= D; dst = C1; }
                    int h = c >> 6, hd = c & 63;
                    dst[(((long)(b * H + h)) * S + s) * HD + hd] = v;
                }
            }
        }
    }
}

// ---------------------------------------------------------------------------
// Scatter cached K/V (H, SC, HD) into K_full/V_full (B,H,S,HD) for both b.
// ---------------------------------------------------------------------------
__global__ __launch_bounds__(256) void scatter_cached(
    const float* __restrict__ kc, const float* __restrict__ vc,
    const int* __restrict__ cidx, float* __restrict__ kf, float* __restrict__ vf)
{
    long e = (long)blockIdx.x * 256 + threadIdx.x;
    if (e >= (long)H * SC * HD) return;
    int hd = e & 63;
    long tmp = e >> 6;
    int j = (int)(tmp % SC);
    int h = (int)(tmp / SC);
    int s = cidx[j];
    float kv = kc[e], vv = vc[e];
    long o0 = (((long)(0 * H + h)) * S + s) * HD + hd;
    long o1 = (((long)(1 * H + h)) * S + s) * HD + hd;
    kf[o0] = kv; kf[o1] = kv;
    vf[o0] = vv; vf[o1] = vv;
}

// ---------------------------------------------------------------------------
// Flash attention: block = 4 waves, each wave owns one query row of one
// (b,h); iterate 64-key tiles staged in LDS; online softmax. (unchanged)
// ---------------------------------------------------------------------------
__global__ __launch_bounds__(256) void attn_kernel(
    const float* __restrict__ q, const float* __restrict__ kf,
    const float* __restrict__ vf, float* __restrict__ ctx)
{
    __shared__ float Ks[64][65];
    __shared__ float Vs[64][65];
    __shared__ float qs[4][64];
    __shared__ float ps[4][64];
    const int t = threadIdx.x;
    const int lane = t & 63, w = t >> 6;
    const int blk = blockIdx.x;
    const int qb = blk % (S / 4);
    const int bh = blk / (S / 4);
    const int qrow = qb * 4 + w;

    qs[w][lane] = q[((long)bh * S + qrow) * HD + lane];

    float m = -1e30f, l = 0.f, acc = 0.f;
    const float scale = 0.125f;   // 1/sqrt(64)
    const float* Kbase = kf + (long)bh * S * HD;
    const float* Vbase = vf + (long)bh * S * HD;

    for (int k0 = 0; k0 < S; k0 += 64) {
        __syncthreads();
#pragma unroll
        for (int i = 0; i < 16; i++) {
            int lidx = i * 256 + t;
            int key = lidx >> 6, hd = lidx & 63;
            Ks[key][hd] = Kbase[(long)(k0 + key) * HD + hd];
            Vs[key][hd] = Vbase[(long)(k0 + key) * HD + hd];
        }
        __syncthreads();

        float s = 0.f;
#pragma unroll
        for (int hd = 0; hd < 64; hd++) s += qs[w][hd] * Ks[lane][hd];
        s *= scale;

        float bm_ = s;
        for (int off = 32; off; off >>= 1) bm_ = fmaxf(bm_, __shfl_xor(bm_, off, 64));
        float mn = fmaxf(m, bm_);
        float p = __expf(s - mn);
        float bl = p;
        for (int off = 32; off; off >>= 1) bl += __shfl_xor(bl, off, 64);
        float c = __expf(m - mn);
        l = l * c + bl;
        m = mn;
        ps[w][lane] = p;

        acc *= c;
#pragma unroll
        for (int j = 0; j < 64; j++) acc += ps[w][j] * Vs[j][lane];
    }
    acc /= l;
    int b = bh / H, h = bh - b * H;
    ctx[((long)(b * S + qrow)) * D + h * HD + lane] = acc;
}

// ---------------------------------------------------------------------------
// LayerNorm: out = LN(a + r) * g + be.  One block per row, 256 thr x 2 cols.
// ---------------------------------------------------------------------------
__global__ __launch_bounds__(256) void ln_kernel(
    const float* __restrict__ a, const float* __restrict__ r,
    const float* __restrict__ g, const float* __restrict__ be,
    float* __restrict__ out)
{
    const long row = blockIdx.x;
    const int t = threadIdx.x;
    const float* pa = a + row * D;
    const float* pr = r + row * D;
    float v0 = pa[t] + pr[t];
    float v1 = pa[t + 256] + pr[t + 256];
    float s1 = v0 + v1, s2 = v0 * v0 + v1 * v1;
    for (int off = 32; off; off >>= 1) {
        s1 += __shfl_xor(s1, off, 64);
        s2 += __shfl_xor(s2, off, 64);
    }
    __shared__ float red[8];
    int w = t >> 6, lane = t & 63;
    if (lane == 0) { red[w] = s1; red[4 + w] = s2; }
    __syncthreads();
    float sum = red[0] + red[1] + red[2] + red[3];
    float ssq = red[4] + red[5] + red[6] + red[7];
    float mean = sum * (1.f / D);
    float var = ssq * (1.f / D) - mean * mean;
    float rstd = rsqrtf(var + EPS);
    out[row * D + t] = (v0 - mean) * rstd * g[t] + be[t];
    out[row * D + t + 256] = (v1 - mean) * rstd * g[t + 256] + be[t + 256];
}

// ---------------------------------------------------------------------------
extern "C" void kernel_launch(void* const* d_in, const int* in_sizes, int n_in,
                              void* d_out, int out_size, void* d_ws, size_t ws_size,
                              hipStream_t stream)
{
    const float* src      = (const float*)d_in[0];
    const int*   rec_idx  = (const int*)d_in[1];
    const int*   cac_idx  = (const int*)d_in[2];
    const float* k_cached = (const float*)d_in[3];
    const float* v_cached = (const float*)d_in[4];
    const float* in_w     = (const float*)d_in[5];
    const float* in_b     = (const float*)d_in[6];
    const float* out_w    = (const float*)d_in[7];
    const float* out_b    = (const float*)d_in[8];
    const float* w1       = (const float*)d_in[9];
    const float* b1       = (const float*)d_in[10];
    const float* w2       = (const float*)d_in[11];
    const float* b2       = (const float*)d_in[12];
    const float* n1w      = (const float*)d_in[13];
    const float* n1b      = (const float*)d_in[14];
    const float* n2w      = (const float*)d_in[15];
    const float* n2b      = (const float*)d_in[16];

    float* ws  = (float*)d_ws;
    float* Q   = ws;                 // B*H*S*HD = 3145728
    float* KF  = ws + 3145728;
    float* VF  = ws + 6291456;
    float* CTX = ws + 9437184;
    float* AO  = ws + 12582912;
    float* X   = ws + 15728640;
    float* HID = ws + 18874368;      // B*S*DFF = 12582912
    float* out = (float*)d_out;

    dim3 blk(256);

    // 1. Q projection: scatter to (B,H,S,HD)
    gemm_mfma<1, 0><<<dim3(D / 64, (B * S) / 64), blk, 0, stream>>>(
        src, in_w, in_b, Q, nullptr, B * S, D, D, nullptr);
    // 2. K/V projection of recomputed rows, scattered into K_full/V_full
    gemm_mfma<2, 0><<<dim3((2 * D) / 64, (B * R) / 64), blk, 0, stream>>>(
        src, in_w + D * D, in_b + D, KF, VF, B * R, 2 * D, D, rec_idx);
    // 3. scatter cached K/V
    scatter_cached<<<dim3((H * SC * HD + 255) / 256), blk, 0, stream>>>(
        k_cached, v_cached, cac_idx, KF, VF);
    // 4. flash attention -> ctx (B,S,D)
    attn_kernel<<<dim3(B * H * (S / 4)), blk, 0, stream>>>(Q, KF, VF, CTX);
    // 5. out projection
    gemm_mfma<0, 0><<<dim3(D / 64, (B * S) / 64), blk, 0, stream>>>(
        CTX, out_w, out_b, AO, nullptr, B * S, D, D, nullptr);
    // 6. LN1: x = LN(src + attn_out)
    ln_kernel<<<dim3(B * S), blk, 0, stream>>>(src, AO, n1w, n1b, X);
    // 7. FFN1 + ReLU
    gemm_mfma<0, 1><<<dim3(DFF / 64, (B * S) / 64), blk, 0, stream>>>(
        X, w1, b1, HID, nullptr, B * S, DFF, D, nullptr);
    // 8. FFN2
    gemm_mfma<0, 0><<<dim3(D / 64, (B * S) / 64), blk, 0, stream>>>(
        HID, w2, b2, AO, nullptr, B * S, D, DFF, nullptr);
    // 9. LN2 -> d_out
    ln_kernel<<<dim3(B * S), blk, 0, stream>>>(X, AO, n2w, n2b, out);
}

// Round 5
// 356.966 us; speedup vs baseline: 8.0055x; 8.0055x over previous
//
#include <hip/hip_runtime.h>
#include <hip/hip_bf16.h>
#include <math.h>

#define B 2
#define S 3072
#define D 512
#define H 8
#define HD 64
#define DFF 2048
#define R 768
#define SC (S - R)
#define EPS 1e-5f

typedef __attribute__((ext_vector_type(8))) short s8v;   // 8 x bf16 bits (4 VGPR)
typedef __attribute__((ext_vector_type(4))) float f4v;   // mfma accumulator

__device__ inline short f2bf(float x) {
    __hip_bfloat16 h = __float2bfloat16(x);
    return __builtin_bit_cast(short, h);
}

// ---------------------------------------------------------------------------
// bf16-MFMA GEMM: C = A @ W^T + bias.  A: MxK row-major fp32 (row gather in
// MODE 2), W: NxK row-major fp32.  64x64 tile, 4 waves (2x2), BK=32.
// MODE 0: fp32 C. MODE 1: bf16 scatter to Q[b,h,s,hd]. MODE 2: bf16 scatter
// K/V to K_full/V_full at recompute_idx positions.
// ---------------------------------------------------------------------------
template<int MODE, int RELU>
__global__ __launch_bounds__(256) void gemm_mfma(
    const float* __restrict__ A, const float* __restrict__ W,
    const float* __restrict__ bias, void* __restrict__ C0v,
    void* __restrict__ C1v, int M, int N, int K,
    const int* __restrict__ gather_idx)
{
    __shared__ short As[64][40];   // 32 used + 8 pad (80B row, 16B aligned)
    __shared__ short Ws[64][40];
    const int t = threadIdx.x;
    const int bm = blockIdx.y * 64, bn = blockIdx.x * 64;
    const int lane = t & 63, wid = t >> 6;
    const int wm = (wid >> 1) * 32, wn = (wid & 1) * 32;  // wave sub-tile
    const int lr = lane & 15, lk = lane >> 4;             // frag row, k-group

    const int srow = t >> 2;
    const int scol = (t & 3) * 8;
    long arow_g;
    if (MODE == 2) {
        int r = bm + srow; int b = r / R, i = r - b * R;
        arow_g = (long)b * S + gather_idx[i];
    } else {
        arow_g = bm + srow;
    }
    const float* Ap = A + arow_g * (long)K + scol;
    const float* Wp = W + (long)(bn + srow) * K + scol;

    f4v acc[2][2] = {};

    for (int k0 = 0; k0 < K; k0 += 32) {
        float4 a0 = *(const float4*)(Ap + k0);
        float4 a1 = *(const float4*)(Ap + k0 + 4);
        float4 w0 = *(const float4*)(Wp + k0);
        float4 w1 = *(const float4*)(Wp + k0 + 4);
        __syncthreads();   // previous tile fully consumed
        s8v av, wv;
        av[0] = f2bf(a0.x); av[1] = f2bf(a0.y); av[2] = f2bf(a0.z); av[3] = f2bf(a0.w);
        av[4] = f2bf(a1.x); av[5] = f2bf(a1.y); av[6] = f2bf(a1.z); av[7] = f2bf(a1.w);
        wv[0] = f2bf(w0.x); wv[1] = f2bf(w0.y); wv[2] = f2bf(w0.z); wv[3] = f2bf(w0.w);
        wv[4] = f2bf(w1.x); wv[5] = f2bf(w1.y); wv[6] = f2bf(w1.z); wv[7] = f2bf(w1.w);
        *(s8v*)&As[srow][scol] = av;
        *(s8v*)&Ws[srow][scol] = wv;
        __syncthreads();
        s8v af0 = *(const s8v*)&As[wm + lr][lk * 8];
        s8v af1 = *(const s8v*)&As[wm + 16 + lr][lk * 8];
        s8v bf0 = *(const s8v*)&Ws[wn + lr][lk * 8];
        s8v bf1 = *(const s8v*)&Ws[wn + 16 + lr][lk * 8];
        acc[0][0] = __builtin_amdgcn_mfma_f32_16x16x32_bf16(af0, bf0, acc[0][0], 0, 0, 0);
        acc[0][1] = __builtin_amdgcn_mfma_f32_16x16x32_bf16(af0, bf1, acc[0][1], 0, 0, 0);
        acc[1][0] = __builtin_amdgcn_mfma_f32_16x16x32_bf16(af1, bf0, acc[1][0], 0, 0, 0);
        acc[1][1] = __builtin_amdgcn_mfma_f32_16x16x32_bf16(af1, bf1, acc[1][1], 0, 0, 0);
    }

    // epilogue: C/D layout col=lane&15, row=(lane>>4)*4+reg
#pragma unroll
    for (int mi = 0; mi < 2; mi++) {
#pragma unroll
        for (int ni = 0; ni < 2; ni++) {
#pragma unroll
            for (int i = 0; i < 4; i++) {
                int m = bm + wm + mi * 16 + lk * 4 + i;
                int n = bn + wn + ni * 16 + lr;
                float v = acc[mi][ni][i] + bias[n];
                if (RELU) v = fmaxf(v, 0.f);
                if (MODE == 0) {
                    ((float*)C0v)[(long)m * N + n] = v;
                } else if (MODE == 1) {     // Q scatter -> bf16 [b,h,s,hd]
                    int b = m / S, s = m - b * S;
                    int h = n >> 6, hd = n & 63;
                    ((short*)C0v)[(((long)(b * H + h)) * S + s) * HD + hd] = f2bf(v);
                } else {                    // KV scatter -> bf16 at recompute pos
                    int b = m / R, i2 = m - b * R;
                    int s = gather_idx[i2];
                    int c = n;
                    short* dst = (short*)C0v;
                    if (c >= D) { c -= D; dst = (short*)C1v; }
                    int h = c >> 6, hd = c & 63;
                    dst[(((long)(b * H + h)) * S + s) * HD + hd] = f2bf(v);
                }
            }
        }
    }
}

// ---------------------------------------------------------------------------
// Scatter cached K/V (H, SC, HD) fp32 into bf16 K_full/V_full (B,H,S,HD).
// ---------------------------------------------------------------------------
__global__ __launch_bounds__(256) void scatter_cached(
    const float* __restrict__ kc, const float* __restrict__ vc,
    const int* __restrict__ cidx, short* __restrict__ kf, short* __restrict__ vf)
{
    long e = (long)blockIdx.x * 256 + threadIdx.x;
    if (e >= (long)H * SC * HD) return;
    int hd = e & 63;
    long tmp = e >> 6;
    int j = (int)(tmp % SC);
    int h = (int)(tmp / SC);
    int s = cidx[j];
    short kv = f2bf(kc[e]), vv = f2bf(vc[e]);
    long o0 = (((long)(0 * H + h)) * S + s) * HD + hd;
    long o1 = (((long)(1 * H + h)) * S + s) * HD + hd;
    kf[o0] = kv; kf[o1] = kv;
    vf[o0] = vv; vf[o1] = vv;
}

// ---------------------------------------------------------------------------
// MFMA flash attention: block = 64 q-rows of one (b,h), 4 waves x 16 rows.
// 64-key tiles: K staged [key][hd], V staged transposed [hd][key]; QK^T and
// PV on mfma_f32_16x16x32_bf16; online softmax in-register; P re-layout via
// per-wave LDS strip.
// ---------------------------------------------------------------------------
__global__ __launch_bounds__(256) void attn_mfma(
    const short* __restrict__ Qb, const short* __restrict__ KF,
    const short* __restrict__ VF, float* __restrict__ ctx)
{
    __shared__ short Ks[64][72];
    __shared__ short Vt[64][72];
    __shared__ short Pl[64][72];
    const int t = threadIdx.x;
    const int lane = t & 63, w = t >> 6;
    const int lr = lane & 15, lk = lane >> 4;
    const int nq = S / 64;                       // 48 q-tiles per (b,h)
    const int qt = blockIdx.x % nq;
    const int bh = blockIdx.x / nq;
    const long base = (long)bh * S;

    // Q A-fragments: row = lr (q within wave's 16), k = 8*lk..+8
    const int qrow = qt * 64 + w * 16 + lr;
    const s8v qf0 = *(const s8v*)&Qb[(base + qrow) * HD + lk * 8];
    const s8v qf1 = *(const s8v*)&Qb[(base + qrow) * HD + 32 + lk * 8];

    f4v od[4] = {};                              // O accum, C-layout, 4 d-subtiles
    float mrow[4], lrow[4];
#pragma unroll
    for (int i = 0; i < 4; i++) { mrow[i] = -1e30f; lrow[i] = 0.f; }
    const float scale = 0.125f;                  // 1/sqrt(64)

    for (int k0 = 0; k0 < S; k0 += 64) {
        __syncthreads();                         // prev tile fully consumed
#pragma unroll
        for (int p = 0; p < 2; p++) {
            int idx = p * 2048 + t * 8;
            int r = idx >> 6, c = idx & 63;
            s8v kv = *(const s8v*)&KF[(base + k0 + r) * HD + c];
            s8v vv = *(const s8v*)&VF[(base + k0 + r) * HD + c];
            *(s8v*)&Ks[r][c] = kv;
#pragma unroll
            for (int j = 0; j < 8; j++) Vt[c + j][r] = vv[j];   // transpose
        }
        __syncthreads();

        // QK^T: wave's 16 q x 64 keys (4 key-subtiles x K=64 via 2 mfma)
        f4v sc[4];
#pragma unroll
        for (int st = 0; st < 4; st++) {
            s8v kf0 = *(const s8v*)&Ks[st * 16 + lr][lk * 8];
            s8v kf1 = *(const s8v*)&Ks[st * 16 + lr][32 + lk * 8];
            f4v a = {};
            a = __builtin_amdgcn_mfma_f32_16x16x32_bf16(qf0, kf0, a, 0, 0, 0);
            a = __builtin_amdgcn_mfma_f32_16x16x32_bf16(qf1, kf1, a, 0, 0, 0);
            sc[st] = a;
        }

        // online softmax; lane holds S[q=lk*4+i][key=st*16+lr]
        float pv[4][4];
#pragma unroll
        for (int st = 0; st < 4; st++)
#pragma unroll
            for (int i = 0; i < 4; i++) pv[st][i] = sc[st][i] * scale;
#pragma unroll
        for (int i = 0; i < 4; i++) {
            float mx = fmaxf(fmaxf(pv[0][i], pv[1][i]), fmaxf(pv[2][i], pv[3][i]));
#pragma unroll
            for (int off = 1; off < 16; off <<= 1) mx = fmaxf(mx, __shfl_xor(mx, off, 64));
            float mn = fmaxf(mrow[i], mx);
            float c = __expf(mrow[i] - mn);
            float s = 0.f;
#pragma unroll
            for (int st = 0; st < 4; st++) { float e = __expf(pv[st][i] - mn); pv[st][i] = e; s += e; }
#pragma unroll
            for (int off = 1; off < 16; off <<= 1) s += __shfl_xor(s, off, 64);
            lrow[i] = lrow[i] * c + s;
            mrow[i] = mn;
#pragma unroll
            for (int dst = 0; dst < 4; dst++) od[dst][i] *= c;
        }

        // P: C-layout -> A-layout via per-wave LDS strip
#pragma unroll
        for (int st = 0; st < 4; st++)
#pragma unroll
            for (int i = 0; i < 4; i++)
                Pl[w * 16 + lk * 4 + i][st * 16 + lr] = f2bf(pv[st][i]);

        s8v pf0 = *(const s8v*)&Pl[w * 16 + lr][lk * 8];
        s8v pf1 = *(const s8v*)&Pl[w * 16 + lr][32 + lk * 8];
#pragma unroll
        for (int dst = 0; dst < 4; dst++) {
            s8v vf0 = *(const s8v*)&Vt[dst * 16 + lr][lk * 8];
            s8v vf1 = *(const s8v*)&Vt[dst * 16 + lr][32 + lk * 8];
            od[dst] = __builtin_amdgcn_mfma_f32_16x16x32_bf16(pf0, vf0, od[dst], 0, 0, 0);
            od[dst] = __builtin_amdgcn_mfma_f32_16x16x32_bf16(pf1, vf1, od[dst], 0, 0, 0);
        }
    }

    const int b = bh / H, h = bh - b * H;
#pragma unroll
    for (int dst = 0; dst < 4; dst++)
#pragma unroll
        for (int i = 0; i < 4; i++) {
            int q = qt * 64 + w * 16 + lk * 4 + i;
            int d = dst * 16 + lr;
            ctx[((long)(b * S + q)) * D + h * HD + d] = od[dst][i] / lrow[i];
        }
}

// ---------------------------------------------------------------------------
// LayerNorm: out = LN(a + r) * g + be.  One block per row, 256 thr x 2 cols.
// ---------------------------------------------------------------------------
__global__ __launch_bounds__(256) void ln_kernel(
    const float* __restrict__ a, const float* __restrict__ r,
    const float* __restrict__ g, const float* __restrict__ be,
    float* __restrict__ out)
{
    const long row = blockIdx.x;
    const int t = threadIdx.x;
    const float* pa = a + row * D;
    const float* pr = r + row * D;
    float v0 = pa[t] + pr[t];
    float v1 = pa[t + 256] + pr[t + 256];
    float s1 = v0 + v1, s2 = v0 * v0 + v1 * v1;
    for (int off = 32; off; off >>= 1) {
        s1 += __shfl_xor(s1, off, 64);
        s2 += __shfl_xor(s2, off, 64);
    }
    __shared__ float red[8];
    int w = t >> 6, lane = t & 63;
    if (lane == 0) { red[w] = s1; red[4 + w] = s2; }
    __syncthreads();
    float sum = red[0] + red[1] + red[2] + red[3];
    float ssq = red[4] + red[5] + red[6] + red[7];
    float mean = sum * (1.f / D);
    float var = ssq * (1.f / D) - mean * mean;
    float rstd = rsqrtf(var + EPS);
    out[row * D + t] = (v0 - mean) * rstd * g[t] + be[t];
    out[row * D + t + 256] = (v1 - mean) * rstd * g[t + 256] + be[t + 256];
}

// ---------------------------------------------------------------------------
extern "C" void kernel_launch(void* const* d_in, const int* in_sizes, int n_in,
                              void* d_out, int out_size, void* d_ws, size_t ws_size,
                              hipStream_t stream)
{
    const float* src      = (const float*)d_in[0];
    const int*   rec_idx  = (const int*)d_in[1];
    const int*   cac_idx  = (const int*)d_in[2];
    const float* k_cached = (const float*)d_in[3];
    const float* v_cached = (const float*)d_in[4];
    const float* in_w     = (const float*)d_in[5];
    const float* in_b     = (const float*)d_in[6];
    const float* out_w    = (const float*)d_in[7];
    const float* out_b    = (const float*)d_in[8];
    const float* w1       = (const float*)d_in[9];
    const float* b1       = (const float*)d_in[10];
    const float* w2       = (const float*)d_in[11];
    const float* b2       = (const float*)d_in[12];
    const float* n1w      = (const float*)d_in[13];
    const float* n1b      = (const float*)d_in[14];
    const float* n2w      = (const float*)d_in[15];
    const float* n2b      = (const float*)d_in[16];

    // workspace layout: bf16 Q/K/V then fp32 intermediates
    short* Qb  = (short*)d_ws;               // 3145728 shorts
    short* KF  = Qb + 3145728;
    short* VF  = KF + 3145728;
    float* CTX = (float*)(VF + 3145728);     // 3145728 floats
    float* AO  = CTX + 3145728;
    float* X   = AO + 3145728;
    float* HID = X + 3145728;                // B*S*DFF floats
    float* out = (float*)d_out;

    dim3 blk(256);

    // 1. Q projection -> bf16 (B,H,S,HD)
    gemm_mfma<1, 0><<<dim3(D / 64, (B * S) / 64), blk, 0, stream>>>(
        src, in_w, in_b, Qb, nullptr, B * S, D, D, nullptr);
    // 2. K/V projection of recomputed rows -> bf16 K_full/V_full
    gemm_mfma<2, 0><<<dim3((2 * D) / 64, (B * R) / 64), blk, 0, stream>>>(
        src, in_w + D * D, in_b + D, KF, VF, B * R, 2 * D, D, rec_idx);
    // 3. scatter cached K/V -> bf16
    scatter_cached<<<dim3((H * SC * HD + 255) / 256), blk, 0, stream>>>(
        k_cached, v_cached, cac_idx, KF, VF);
    // 4. MFMA flash attention -> ctx (B,S,D) fp32
    attn_mfma<<<dim3(B * H * (S / 64)), blk, 0, stream>>>(Qb, KF, VF, CTX);
    // 5. out projection
    gemm_mfma<0, 0><<<dim3(D / 64, (B * S) / 64), blk, 0, stream>>>(
        CTX, out_w, out_b, AO, nullptr, B * S, D, D, nullptr);
    // 6. LN1: x = LN(src + attn_out)
    ln_kernel<<<dim3(B * S), blk, 0, stream>>>(src, AO, n1w, n1b, X);
    // 7. FFN1 + ReLU
    gemm_mfma<0, 1><<<dim3(DFF / 64, (B * S) / 64), blk, 0, stream>>>(
        X, w1, b1, HID, nullptr, B * S, DFF, D, nullptr);
    // 8. FFN2
    gemm_mfma<0, 0><<<dim3(D / 64, (B * S) / 64), blk, 0, stream>>>(
        HID, w2, b2, AO, nullptr, B * S, D, DFF, nullptr);
    // 9. LN2 -> d_out
    ln_kernel<<<dim3(B * S), blk, 0, stream>>>(X, AO, n2w, n2b, out);
}

// Round 6
// 301.309 us; speedup vs baseline: 9.4843x; 1.1847x over previous
//
#include <hip/hip_runtime.h>
#include <hip/hip_bf16.h>
#include <math.h>

#define B 2
#define S 3072
#define D 512
#define H 8
#define HD 64
#define DFF 2048
#define R 768
#define SC (S - R)
#define EPS 1e-5f

typedef __attribute__((ext_vector_type(8))) short s8v;   // 8 x bf16 bits (4 VGPR)
typedef __attribute__((ext_vector_type(4))) float f4v;   // mfma accumulator

__device__ inline short f2bf(float x) {
    __hip_bfloat16 h = __float2bfloat16(x);
    return __builtin_bit_cast(short, h);
}
__device__ inline unsigned int pack2bf(float a, float b) {
    return (unsigned int)(unsigned short)f2bf(a) |
           ((unsigned int)(unsigned short)f2bf(b) << 16);
}

// ---------------------------------------------------------------------------
// bf16-MFMA GEMM: C = A @ W^T + bias.  A: MxK row-major fp32 (row gather in
// MODE 2), W: NxK row-major fp32.  64x64 tile, 4 waves (2x2), BK=32.
// MODE 0: fp32 C. MODE 1: bf16 scatter to Q[b,h,s,hd]. MODE 2: bf16 scatter
// K -> K_full[b,h,s,hd], V -> V^T[b,h,hd,s] at recompute_idx positions.
// ---------------------------------------------------------------------------
template<int MODE, int RELU>
__global__ __launch_bounds__(256) void gemm_mfma(
    const float* __restrict__ A, const float* __restrict__ W,
    const float* __restrict__ bias, void* __restrict__ C0v,
    void* __restrict__ C1v, int M, int N, int K,
    const int* __restrict__ gather_idx)
{
    __shared__ short As[64][40];
    __shared__ short Ws[64][40];
    const int t = threadIdx.x;
    const int bm = blockIdx.y * 64, bn = blockIdx.x * 64;
    const int lane = t & 63, wid = t >> 6;
    const int wm = (wid >> 1) * 32, wn = (wid & 1) * 32;
    const int lr = lane & 15, lk = lane >> 4;

    const int srow = t >> 2;
    const int scol = (t & 3) * 8;
    long arow_g;
    if (MODE == 2) {
        int r = bm + srow; int b = r / R, i = r - b * R;
        arow_g = (long)b * S + gather_idx[i];
    } else {
        arow_g = bm + srow;
    }
    const float* Ap = A + arow_g * (long)K + scol;
    const float* Wp = W + (long)(bn + srow) * K + scol;

    f4v acc[2][2] = {};

    for (int k0 = 0; k0 < K; k0 += 32) {
        float4 a0 = *(const float4*)(Ap + k0);
        float4 a1 = *(const float4*)(Ap + k0 + 4);
        float4 w0 = *(const float4*)(Wp + k0);
        float4 w1 = *(const float4*)(Wp + k0 + 4);
        __syncthreads();
        s8v av, wv;
        av[0] = f2bf(a0.x); av[1] = f2bf(a0.y); av[2] = f2bf(a0.z); av[3] = f2bf(a0.w);
        av[4] = f2bf(a1.x); av[5] = f2bf(a1.y); av[6] = f2bf(a1.z); av[7] = f2bf(a1.w);
        wv[0] = f2bf(w0.x); wv[1] = f2bf(w0.y); wv[2] = f2bf(w0.z); wv[3] = f2bf(w0.w);
        wv[4] = f2bf(w1.x); wv[5] = f2bf(w1.y); wv[6] = f2bf(w1.z); wv[7] = f2bf(w1.w);
        *(s8v*)&As[srow][scol] = av;
        *(s8v*)&Ws[srow][scol] = wv;
        __syncthreads();
        s8v af0 = *(const s8v*)&As[wm + lr][lk * 8];
        s8v af1 = *(const s8v*)&As[wm + 16 + lr][lk * 8];
        s8v bf0 = *(const s8v*)&Ws[wn + lr][lk * 8];
        s8v bf1 = *(const s8v*)&Ws[wn + 16 + lr][lk * 8];
        acc[0][0] = __builtin_amdgcn_mfma_f32_16x16x32_bf16(af0, bf0, acc[0][0], 0, 0, 0);
        acc[0][1] = __builtin_amdgcn_mfma_f32_16x16x32_bf16(af0, bf1, acc[0][1], 0, 0, 0);
        acc[1][0] = __builtin_amdgcn_mfma_f32_16x16x32_bf16(af1, bf0, acc[1][0], 0, 0, 0);
        acc[1][1] = __builtin_amdgcn_mfma_f32_16x16x32_bf16(af1, bf1, acc[1][1], 0, 0, 0);
    }

#pragma unroll
    for (int mi = 0; mi < 2; mi++) {
#pragma unroll
        for (int ni = 0; ni < 2; ni++) {
#pragma unroll
            for (int i = 0; i < 4; i++) {
                int m = bm + wm + mi * 16 + lk * 4 + i;
                int n = bn + wn + ni * 16 + lr;
                float v = acc[mi][ni][i] + bias[n];
                if (RELU) v = fmaxf(v, 0.f);
                if (MODE == 0) {
                    ((float*)C0v)[(long)m * N + n] = v;
                } else if (MODE == 1) {     // Q scatter -> bf16 [b,h,s,hd]
                    int b = m / S, s = m - b * S;
                    int h = n >> 6, hd = n & 63;
                    ((short*)C0v)[(((long)(b * H + h)) * S + s) * HD + hd] = f2bf(v);
                } else {                    // K row-major / V transposed
                    int b = m / R, i2 = m - b * R;
                    int s = gather_idx[i2];
                    int c = n;
                    if (c < D) {
                        int h = c >> 6, hd = c & 63;
                        ((short*)C0v)[(((long)(b * H + h)) * S + s) * HD + hd] = f2bf(v);
                    } else {
                        c -= D;
                        int h = c >> 6, hd = c & 63;
                        ((short*)C1v)[(((long)(b * H + h)) * HD + hd) * S + s] = f2bf(v);
                    }
                }
            }
        }
    }
}

// ---------------------------------------------------------------------------
// Cached K scatter: (H,SC,HD) fp32 -> bf16 K_full[b,h,s,hd], both b.
// ---------------------------------------------------------------------------
__global__ __launch_bounds__(256) void scatter_cached_k(
    const float* __restrict__ kc, const int* __restrict__ cidx,
    short* __restrict__ kf)
{
    long e = (long)blockIdx.x * 256 + threadIdx.x;
    if (e >= (long)H * SC * HD) return;
    int hd = e & 63;
    long tmp = e >> 6;
    int j = (int)(tmp % SC);
    int h = (int)(tmp / SC);
    int s = cidx[j];
    short v = f2bf(kc[e]);
    kf[(((long)(0 * H + h)) * S + s) * HD + hd] = v;
    kf[(((long)(1 * H + h)) * S + s) * HD + hd] = v;
}

// ---------------------------------------------------------------------------
// Cached V scatter to V^T[b,h,hd,s].  Lanes = hd (coalesced reads); each
// thread walks 16 consecutive j (sorted cidx -> near-sequential s writes,
// L2 coalesces the stride-S short writes).
// ---------------------------------------------------------------------------
__global__ __launch_bounds__(256) void scatter_cached_vT(
    const float* __restrict__ vc, const int* __restrict__ cidx,
    short* __restrict__ vt)
{
    const int hd = threadIdx.x & 63, jg = threadIdx.x >> 6;
    const int h = blockIdx.y;
    const int j0 = blockIdx.x * 64 + jg * 16;
#pragma unroll 4
    for (int jj = 0; jj < 16; jj++) {
        int j = j0 + jj;
        int s = cidx[j];
        short v = f2bf(vc[((long)h * SC + j) * HD + hd]);
        vt[(((long)(0 * H + h)) * HD + hd) * S + s] = v;
        vt[(((long)(1 * H + h)) * HD + hd) * S + s] = v;
    }
}

// ---------------------------------------------------------------------------
// MFMA flash attention, split-K over 2 key-halves.  Block = 64 q-rows of one
// (b,h), 4 waves x 16 q.  S^T = mfma(K,Q) so each lane owns 16 scores of one
// q-row (in-lane softmax); P re-laid to A-frags via 16 shfl + selects (no
// LDS roundtrip).  V^T read directly from global (pre-transposed).
// Outputs partial O and (m,l) per q-row for the combine pass.
// ---------------------------------------------------------------------------
__global__ __launch_bounds__(256) void attn_mfma(
    const short* __restrict__ Qb, const short* __restrict__ KF,
    const short* __restrict__ VT, float* __restrict__ Opart,
    float* __restrict__ ML)
{
    __shared__ short Ks[64][72];
    __shared__ short Vt[64][72];
    const int t = threadIdx.x;
    const int lane = t & 63, w = t >> 6;
    const int lr = lane & 15, lk = lane >> 4;
    const int nq = S / 64;
    const int qt = blockIdx.x % nq;
    const int bh = blockIdx.x / nq;
    const int kh = blockIdx.y;
    const long base = (long)bh * S;

    const int qrow = qt * 64 + w * 16 + lr;
    const s8v qf0 = *(const s8v*)&Qb[(base + qrow) * HD + lk * 8];
    const s8v qf1 = *(const s8v*)&Qb[(base + qrow) * HD + 32 + lk * 8];

    f4v od[4] = {};
    float m = -1e30f, l = 0.f;
    const float scale = 0.125f;
    const bool hi = (lane & 32) != 0;
    const int sA = (((lk * 2) & 3) << 4) | lr;
    const int sB = (((lk * 2 + 1) & 3) << 4) | lr;

    const int kbeg = kh * (S / 2), kend = kbeg + S / 2;
    for (int k0 = kbeg; k0 < kend; k0 += 64) {
        __syncthreads();                 // prev tile's LDS reads done
#pragma unroll
        for (int p = 0; p < 2; p++) {
            int idx = p * 2048 + t * 8;
            int r = idx >> 6, c = idx & 63;
            *(s8v*)&Ks[r][c] = *(const s8v*)&KF[(base + k0 + r) * HD + c];
            *(s8v*)&Vt[r][c] = *(const s8v*)&VT[((long)bh * HD + r) * S + k0 + c];
        }
        __syncthreads();

        // S^T: lane holds S[q=lr][key = st*16 + lk*4 + i]
        f4v sc[4];
#pragma unroll
        for (int st = 0; st < 4; st++) {
            s8v kf0 = *(const s8v*)&Ks[st * 16 + lr][lk * 8];
            s8v kf1 = *(const s8v*)&Ks[st * 16 + lr][32 + lk * 8];
            f4v a = {};
            a = __builtin_amdgcn_mfma_f32_16x16x32_bf16(kf0, qf0, a, 0, 0, 0);
            a = __builtin_amdgcn_mfma_f32_16x16x32_bf16(kf1, qf1, a, 0, 0, 0);
            sc[st] = a;
        }

        // online softmax for q=lr (replicated over the 4 lk lanes)
        float ps_[4][4];
        float tmax = -1e30f;
#pragma unroll
        for (int st = 0; st < 4; st++)
#pragma unroll
            for (int i = 0; i < 4; i++) {
                float v = sc[st][i] * scale;
                ps_[st][i] = v;
                tmax = fmaxf(tmax, v);
            }
        tmax = fmaxf(tmax, __shfl_xor(tmax, 16, 64));
        tmax = fmaxf(tmax, __shfl_xor(tmax, 32, 64));
        float mn = fmaxf(m, tmax);
        float cq = __expf(m - mn);
        m = mn;
        float rs = 0.f;
#pragma unroll
        for (int st = 0; st < 4; st++)
#pragma unroll
            for (int i = 0; i < 4; i++) {
                float e = __expf(ps_[st][i] - mn);
                ps_[st][i] = e;
                rs += e;
            }
        rs += __shfl_xor(rs, 16, 64);
        rs += __shfl_xor(rs, 32, 64);
        l = l * cq + rs;

        // rescale O: od rows are q = lk*4+i -> pull that q's cq
#pragma unroll
        for (int i = 0; i < 4; i++) {
            float ci = __shfl(cq, (lane & 48) | (lk * 4 + i), 64);
#pragma unroll
            for (int dst = 0; dst < 4; dst++) od[dst][i] *= ci;
        }

        // pack P (bf16 pairs): pd[st*2+i2] = keys st*16+lk*4+{2i2,2i2+1}
        unsigned int pd0 = pack2bf(ps_[0][0], ps_[0][1]);
        unsigned int pd1 = pack2bf(ps_[0][2], ps_[0][3]);
        unsigned int pd2 = pack2bf(ps_[1][0], ps_[1][1]);
        unsigned int pd3 = pack2bf(ps_[1][2], ps_[1][3]);
        unsigned int pd4 = pack2bf(ps_[2][0], ps_[2][1]);
        unsigned int pd5 = pack2bf(ps_[2][2], ps_[2][3]);
        unsigned int pd6 = pack2bf(ps_[3][0], ps_[3][1]);
        unsigned int pd7 = pack2bf(ps_[3][2], ps_[3][3]);

        // exchange -> A-frag: lane (lr,lk) gets P[q=lr][keys m*32+lk*8 .. +8]
        int s0 = __shfl((int)pd0, sA, 64), s2 = __shfl((int)pd2, sA, 64);
        int s1 = __shfl((int)pd1, sA, 64), s3 = __shfl((int)pd3, sA, 64);
        int u0 = __shfl((int)pd0, sB, 64), u2 = __shfl((int)pd2, sB, 64);
        int u1 = __shfl((int)pd1, sB, 64), u3 = __shfl((int)pd3, sB, 64);
        int T00 = hi ? s2 : s0, T01 = hi ? s3 : s1;
        int T02 = hi ? u2 : u0, T03 = hi ? u3 : u1;
        int s4 = __shfl((int)pd4, sA, 64), s6 = __shfl((int)pd6, sA, 64);
        int s5 = __shfl((int)pd5, sA, 64), s7 = __shfl((int)pd7, sA, 64);
        int u4 = __shfl((int)pd4, sB, 64), u6 = __shfl((int)pd6, sB, 64);
        int u5 = __shfl((int)pd5, sB, 64), u7 = __shfl((int)pd7, sB, 64);
        int T10 = hi ? s6 : s4, T11 = hi ? s7 : s5;
        int T12 = hi ? u6 : u4, T13 = hi ? u7 : u5;

        int4 w0 = {T00, T01, T02, T03};
        int4 w1 = {T10, T11, T12, T13};
        s8v pf0 = __builtin_bit_cast(s8v, w0);
        s8v pf1 = __builtin_bit_cast(s8v, w1);

        // PV: O[q][d], A=P (rows q), B=V^T (cols d)
#pragma unroll
        for (int dst = 0; dst < 4; dst++) {
            s8v vf0 = *(const s8v*)&Vt[dst * 16 + lr][lk * 8];
            s8v vf1 = *(const s8v*)&Vt[dst * 16 + lr][32 + lk * 8];
            od[dst] = __builtin_amdgcn_mfma_f32_16x16x32_bf16(pf0, vf0, od[dst], 0, 0, 0);
            od[dst] = __builtin_amdgcn_mfma_f32_16x16x32_bf16(pf1, vf1, od[dst], 0, 0, 0);
        }
    }

    // partial outputs
    const long pb = ((long)(kh * 16 + bh)) * S;
    if (lk == 0) {
        int q = qt * 64 + w * 16 + lr;
        ML[(pb + q) * 2 + 0] = m;
        ML[(pb + q) * 2 + 1] = l;
    }
#pragma unroll
    for (int dst = 0; dst < 4; dst++)
#pragma unroll
        for (int i = 0; i < 4; i++) {
            int q = qt * 64 + w * 16 + lk * 4 + i;
            int d = dst * 16 + lr;
            Opart[(pb + q) * HD + d] = od[dst][i];
        }
}

// ---------------------------------------------------------------------------
// Combine the two key-half partials -> ctx (B,S,D) fp32.
// ---------------------------------------------------------------------------
__global__ __launch_bounds__(256) void attn_combine(
    const float* __restrict__ Opart, const float* __restrict__ ML,
    float* __restrict__ ctx)
{
    long idx = (long)blockIdx.x * 256 + threadIdx.x;   // B*H*S*HD/4 threads
    long f = idx * 4;
    int d = (int)(f & 63);
    long x = f >> 6;                                   // bh*S + q
    int bh = (int)(x / S);
    int q = (int)(x - (long)bh * S);
    long x1 = x + (long)16 * S;
    float m0 = ML[x * 2], l0 = ML[x * 2 + 1];
    float m1 = ML[x1 * 2], l1 = ML[x1 * 2 + 1];
    float mm = fmaxf(m0, m1);
    float e0 = __expf(m0 - mm), e1 = __expf(m1 - mm);
    float inv = 1.f / (l0 * e0 + l1 * e1);
    float4 o0 = *(const float4*)&Opart[x * HD + d];
    float4 o1 = *(const float4*)&Opart[x1 * HD + d];
    int b = bh >> 3, h = bh & 7;
    float4 r;
    r.x = (o0.x * e0 + o1.x * e1) * inv;
    r.y = (o0.y * e0 + o1.y * e1) * inv;
    r.z = (o0.z * e0 + o1.z * e1) * inv;
    r.w = (o0.w * e0 + o1.w * e1) * inv;
    *(float4*)&ctx[((long)(b * S + q)) * D + h * HD + d] = r;
}

// ---------------------------------------------------------------------------
// LayerNorm: out = LN(a + r) * g + be.
// ---------------------------------------------------------------------------
__global__ __launch_bounds__(256) void ln_kernel(
    const float* __restrict__ a, const float* __restrict__ r,
    const float* __restrict__ g, const float* __restrict__ be,
    float* __restrict__ out)
{
    const long row = blockIdx.x;
    const int t = threadIdx.x;
    const float* pa = a + row * D;
    const float* pr = r + row * D;
    float v0 = pa[t] + pr[t];
    float v1 = pa[t + 256] + pr[t + 256];
    float s1 = v0 + v1, s2 = v0 * v0 + v1 * v1;
    for (int off = 32; off; off >>= 1) {
        s1 += __shfl_xor(s1, off, 64);
        s2 += __shfl_xor(s2, off, 64);
    }
    __shared__ float red[8];
    int w = t >> 6, lane = t & 63;
    if (lane == 0) { red[w] = s1; red[4 + w] = s2; }
    __syncthreads();
    float sum = red[0] + red[1] + red[2] + red[3];
    float ssq = red[4] + red[5] + red[6] + red[7];
    float mean = sum * (1.f / D);
    float var = ssq * (1.f / D) - mean * mean;
    float rstd = rsqrtf(var + EPS);
    out[row * D + t] = (v0 - mean) * rstd * g[t] + be[t];
    out[row * D + t + 256] = (v1 - mean) * rstd * g[t + 256] + be[t + 256];
}

// ---------------------------------------------------------------------------
extern "C" void kernel_launch(void* const* d_in, const int* in_sizes, int n_in,
                              void* d_out, int out_size, void* d_ws, size_t ws_size,
                              hipStream_t stream)
{
    const float* src      = (const float*)d_in[0];
    const int*   rec_idx  = (const int*)d_in[1];
    const int*   cac_idx  = (const int*)d_in[2];
    const float* k_cached = (const float*)d_in[3];
    const float* v_cached = (const float*)d_in[4];
    const float* in_w     = (const float*)d_in[5];
    const float* in_b     = (const float*)d_in[6];
    const float* out_w    = (const float*)d_in[7];
    const float* out_b    = (const float*)d_in[8];
    const float* w1       = (const float*)d_in[9];
    const float* b1       = (const float*)d_in[10];
    const float* w2       = (const float*)d_in[11];
    const float* b2       = (const float*)d_in[12];
    const float* n1w      = (const float*)d_in[13];
    const float* n1b      = (const float*)d_in[14];
    const float* n2w      = (const float*)d_in[15];
    const float* n2b      = (const float*)d_in[16];

    short* Qb  = (short*)d_ws;               // 3145728 shorts
    short* KF  = Qb + 3145728;
    short* VT  = KF + 3145728;               // V^T [b,h,hd,s]
    float* CTX = (float*)(VT + 3145728);
    float* AO  = CTX + 3145728;
    float* X   = AO + 3145728;
    float* HID = X + 3145728;                // 12582912 f (FFN hidden)
    float* Opart = HID;                      // alias: 6291456 f, freed pre-FFN1
    float* ML  = HID + 12582912;             // 196608 f
    float* out = (float*)d_out;

    dim3 blk(256);

    // 1. Q projection -> bf16 (B,H,S,HD)
    gemm_mfma<1, 0><<<dim3(D / 64, (B * S) / 64), blk, 0, stream>>>(
        src, in_w, in_b, Qb, nullptr, B * S, D, D, nullptr);
    // 2. K/V projection of recomputed rows -> K_full / V^T
    gemm_mfma<2, 0><<<dim3((2 * D) / 64, (B * R) / 64), blk, 0, stream>>>(
        src, in_w + D * D, in_b + D, KF, VT, B * R, 2 * D, D, rec_idx);
    // 3. scatter cached K (row-major) and V (transposed)
    scatter_cached_k<<<dim3((H * SC * HD + 255) / 256), blk, 0, stream>>>(
        k_cached, cac_idx, KF);
    scatter_cached_vT<<<dim3(SC / 64, H), blk, 0, stream>>>(
        v_cached, cac_idx, VT);
    // 4. split-K flash attention (2 key-halves) + combine -> CTX
    attn_mfma<<<dim3(B * H * (S / 64), 2), blk, 0, stream>>>(
        Qb, KF, VT, Opart, ML);
    attn_combine<<<dim3((B * H * S * HD / 4) / 256), blk, 0, stream>>>(
        Opart, ML, CTX);
    // 5. out projection
    gemm_mfma<0, 0><<<dim3(D / 64, (B * S) / 64), blk, 0, stream>>>(
        CTX, out_w, out_b, AO, nullptr, B * S, D, D, nullptr);
    // 6. LN1: x = LN(src + attn_out)
    ln_kernel<<<dim3(B * S), blk, 0, stream>>>(src, AO, n1w, n1b, X);
    // 7. FFN1 + ReLU
    gemm_mfma<0, 1><<<dim3(DFF / 64, (B * S) / 64), blk, 0, stream>>>(
        X, w1, b1, HID, nullptr, B * S, DFF, D, nullptr);
    // 8. FFN2
    gemm_mfma<0, 0><<<dim3(D / 64, (B * S) / 64), blk, 0, stream>>>(
        HID, w2, b2, AO, nullptr, B * S, D, DFF, nullptr);
    // 9. LN2 -> d_out
    ln_kernel<<<dim3(B * S), blk, 0, stream>>>(X, AO, n2w, n2b, out);
}

// Round 8
// 289.319 us; speedup vs baseline: 9.8773x; 1.0414x over previous
//
#include <hip/hip_runtime.h>
#include <hip/hip_bf16.h>
#include <cstdint>
#include <math.h>

#define B 2
#define S 3072
#define D 512
#define H 8
#define HD 64
#define DFF 2048
#define R 768
#define SC (S - R)
#define EPS 1e-5f

typedef __attribute__((ext_vector_type(8))) short s8v;   // 8 x bf16 bits (4 VGPR)
typedef __attribute__((ext_vector_type(4))) float f4v;   // mfma accumulator

__device__ inline short f2bf(float x) {
    __hip_bfloat16 h = __float2bfloat16(x);
    return __builtin_bit_cast(short, h);
}
__device__ inline unsigned int pack2bf(float a, float b) {
    return (unsigned int)(unsigned short)f2bf(a) |
           ((unsigned int)(unsigned short)f2bf(b) << 16);
}

// global -> LDS direct 16B load (CK-style addrspace casts via uintptr_t:
// AS3 ptr is the low-32 LDS offset, so the truncating cast is correct).
__device__ __forceinline__ void gload16(const short* g, short* l) {
    auto l3 = reinterpret_cast<__attribute__((address_space(3))) short*>(
        reinterpret_cast<uintptr_t>(l));
    auto g1 = reinterpret_cast<const __attribute__((address_space(1))) short*>(
        reinterpret_cast<uintptr_t>(g));
    __builtin_amdgcn_global_load_lds(g1, l3, 16, 0, 0);
}

// ---------------------------------------------------------------------------
// fp32 -> bf16 convert (n multiple of 4)
// ---------------------------------------------------------------------------
__global__ __launch_bounds__(256) void f2b_kernel(
    const float* __restrict__ in, short* __restrict__ out, int n)
{
    int i = (blockIdx.x * 256 + threadIdx.x) * 4;
    if (i >= n) return;
    float4 v = *(const float4*)(in + i);
    short4 o = { f2bf(v.x), f2bf(v.y), f2bf(v.z), f2bf(v.w) };
    *(short4*)(out + i) = o;
}

// ---------------------------------------------------------------------------
// 128x128 bf16 MFMA GEMM (m97 structure): C = A @ W^T + bias.
// A: MxK bf16 row-major (row gather in MODE 2), W: NxK bf16 row-major.
// global_load_lds(16B) staging, XOR-swizzled LDS (slot = chunk ^ (row&3)),
// BK=32, 4 waves each 64x64 (4x4 fragments of 16x16x32).
// MODE 0: C [M][N] (fp32, or bf16 if OUTBF). MODE 1: bf16 Q scatter.
// MODE 2: bf16 K row-major + V^T scatter at recompute positions.
// ---------------------------------------------------------------------------
template<int MODE, int RELU, int OUTBF>
__global__ __launch_bounds__(256) void gemm128(
    const short* __restrict__ A, const short* __restrict__ W,
    const float* __restrict__ bias, void* __restrict__ C0v,
    void* __restrict__ C1v, int M, int N, int K,
    const int* __restrict__ gather_idx)
{
    __shared__ short Al[128 * 32];
    __shared__ short Bl[128 * 32];
    const int t = threadIdx.x;
    const int bm = blockIdx.y * 128, bn = blockIdx.x * 128;
    const int lane = t & 63, w = t >> 6;
    const int wm = (w >> 1) * 64, wn = (w & 1) * 64;
    const int lr = lane & 15, lk = lane >> 4;

    // staging chunks: LDS chunk q (row q>>2, slot q&3) holds global k-chunk
    // (q&3)^(row&3).  Thread stages chunks t and t+256 of both A and B.
    const int q1 = t, q2 = t + 256;
    const int r1 = q1 >> 2, c1 = (q1 & 3) ^ (r1 & 3);
    const int r2 = q2 >> 2, c2 = (q2 & 3) ^ (r2 & 3);
    long ga1, ga2;
    if (MODE == 2) {
        int m1 = bm + r1; int b1 = m1 >= R; int i1 = m1 - b1 * R;
        ga1 = ((long)b1 * S + gather_idx[i1]) * K + c1 * 8;
        int m2 = bm + r2; int b2 = m2 >= R; int i2 = m2 - b2 * R;
        ga2 = ((long)b2 * S + gather_idx[i2]) * K + c2 * 8;
    } else {
        ga1 = (long)(bm + r1) * K + c1 * 8;
        ga2 = (long)(bm + r2) * K + c2 * 8;
    }
    const long gb1 = (long)(bn + r1) * K + c1 * 8;
    const long gb2 = (long)(bn + r2) * K + c2 * 8;

    f4v acc[4][4] = {};

    for (int k0 = 0; k0 < K; k0 += 32) {
        __syncthreads();                       // prev tile's ds_reads done
        gload16(A + ga1 + k0, Al + q1 * 8);
        gload16(A + ga2 + k0, Al + q2 * 8);
        gload16(W + gb1 + k0, Bl + q1 * 8);
        gload16(W + gb2 + k0, Bl + q2 * 8);
        __syncthreads();                       // vmcnt drained by compiler

        s8v af[4], bf[4];
#pragma unroll
        for (int mi = 0; mi < 4; mi++) {
            int ra = wm + mi * 16 + lr;
            af[mi] = *(const s8v*)&Al[ra * 32 + ((lk ^ (ra & 3)) * 8)];
        }
#pragma unroll
        for (int ni = 0; ni < 4; ni++) {
            int rb = wn + ni * 16 + lr;
            bf[ni] = *(const s8v*)&Bl[rb * 32 + ((lk ^ (rb & 3)) * 8)];
        }
#pragma unroll
        for (int mi = 0; mi < 4; mi++)
#pragma unroll
            for (int ni = 0; ni < 4; ni++)
                acc[mi][ni] = __builtin_amdgcn_mfma_f32_16x16x32_bf16(
                    af[mi], bf[ni], acc[mi][ni], 0, 0, 0);
    }

    // epilogue: C/D layout col=lane&15, row=(lane>>4)*4+reg
#pragma unroll
    for (int mi = 0; mi < 4; mi++) {
#pragma unroll
        for (int ni = 0; ni < 4; ni++) {
#pragma unroll
            for (int i = 0; i < 4; i++) {
                int m = bm + wm + mi * 16 + lk * 4 + i;
                int n = bn + wn + ni * 16 + lr;
                float v = acc[mi][ni][i] + bias[n];
                if (RELU) v = fmaxf(v, 0.f);
                if (MODE == 0) {
                    if (OUTBF) ((short*)C0v)[(long)m * N + n] = f2bf(v);
                    else       ((float*)C0v)[(long)m * N + n] = v;
                } else if (MODE == 1) {     // Q scatter -> bf16 [b,h,s,hd]
                    int b = m >= S; int s = m - b * S;
                    int h = n >> 6, hd = n & 63;
                    ((short*)C0v)[(((long)(b * H + h)) * S + s) * HD + hd] = f2bf(v);
                } else {                    // K row-major / V transposed
                    int b = m >= R; int i2 = m - b * R;
                    int s = gather_idx[i2];
                    int c = n;
                    if (c < D) {
                        int h = c >> 6, hd = c & 63;
                        ((short*)C0v)[(((long)(b * H + h)) * S + s) * HD + hd] = f2bf(v);
                    } else {
                        c -= D;
                        int h = c >> 6, hd = c & 63;
                        ((short*)C1v)[(((long)(b * H + h)) * HD + hd) * S + s] = f2bf(v);
                    }
                }
            }
        }
    }
}

// ---------------------------------------------------------------------------
// Cached K scatter: (H,SC,HD) fp32 -> bf16 K_full[b,h,s,hd], both b.
// ---------------------------------------------------------------------------
__global__ __launch_bounds__(256) void scatter_cached_k(
    const float* __restrict__ kc, const int* __restrict__ cidx,
    short* __restrict__ kf)
{
    long e = (long)blockIdx.x * 256 + threadIdx.x;
    if (e >= (long)H * SC * HD) return;
    int hd = e & 63;
    long tmp = e >> 6;
    int j = (int)(tmp % SC);
    int h = (int)(tmp / SC);
    int s = cidx[j];
    short v = f2bf(kc[e]);
    kf[(((long)(0 * H + h)) * S + s) * HD + hd] = v;
    kf[(((long)(1 * H + h)) * S + s) * HD + hd] = v;
}

// ---------------------------------------------------------------------------
// Cached V scatter to V^T[b,h,hd,s].
// ---------------------------------------------------------------------------
__global__ __launch_bounds__(256) void scatter_cached_vT(
    const float* __restrict__ vc, const int* __restrict__ cidx,
    short* __restrict__ vt)
{
    const int hd = threadIdx.x & 63, jg = threadIdx.x >> 6;
    const int h = blockIdx.y;
    const int j0 = blockIdx.x * 64 + jg * 16;
#pragma unroll 4
    for (int jj = 0; jj < 16; jj++) {
        int j = j0 + jj;
        int s = cidx[j];
        short v = f2bf(vc[((long)h * SC + j) * HD + hd]);
        vt[(((long)(0 * H + h)) * HD + hd) * S + s] = v;
        vt[(((long)(1 * H + h)) * HD + hd) * S + s] = v;
    }
}

// ---------------------------------------------------------------------------
// MFMA flash attention, split-K over 2 key-halves (unchanged, verified R6).
// ---------------------------------------------------------------------------
__global__ __launch_bounds__(256) void attn_mfma(
    const short* __restrict__ Qb, const short* __restrict__ KF,
    const short* __restrict__ VT, float* __restrict__ Opart,
    float* __restrict__ ML)
{
    __shared__ short Ks[64][72];
    __shared__ short Vt[64][72];
    const int t = threadIdx.x;
    const int lane = t & 63, w = t >> 6;
    const int lr = lane & 15, lk = lane >> 4;
    const int nq = S / 64;
    const int qt = blockIdx.x % nq;
    const int bh = blockIdx.x / nq;
    const int kh = blockIdx.y;
    const long base = (long)bh * S;

    const int qrow = qt * 64 + w * 16 + lr;
    const s8v qf0 = *(const s8v*)&Qb[(base + qrow) * HD + lk * 8];
    const s8v qf1 = *(const s8v*)&Qb[(base + qrow) * HD + 32 + lk * 8];

    f4v od[4] = {};
    float m = -1e30f, l = 0.f;
    const float scale = 0.125f;
    const bool hi = (lane & 32) != 0;
    const int sA = (((lk * 2) & 3) << 4) | lr;
    const int sB = (((lk * 2 + 1) & 3) << 4) | lr;

    const int kbeg = kh * (S / 2), kend = kbeg + S / 2;
    for (int k0 = kbeg; k0 < kend; k0 += 64) {
        __syncthreads();
#pragma unroll
        for (int p = 0; p < 2; p++) {
            int idx = p * 2048 + t * 8;
            int r = idx >> 6, c = idx & 63;
            *(s8v*)&Ks[r][c] = *(const s8v*)&KF[(base + k0 + r) * HD + c];
            *(s8v*)&Vt[r][c] = *(const s8v*)&VT[((long)bh * HD + r) * S + k0 + c];
        }
        __syncthreads();

        f4v sc[4];
#pragma unroll
        for (int st = 0; st < 4; st++) {
            s8v kf0 = *(const s8v*)&Ks[st * 16 + lr][lk * 8];
            s8v kf1 = *(const s8v*)&Ks[st * 16 + lr][32 + lk * 8];
            f4v a = {};
            a = __builtin_amdgcn_mfma_f32_16x16x32_bf16(kf0, qf0, a, 0, 0, 0);
            a = __builtin_amdgcn_mfma_f32_16x16x32_bf16(kf1, qf1, a, 0, 0, 0);
            sc[st] = a;
        }

        float ps_[4][4];
        float tmax = -1e30f;
#pragma unroll
        for (int st = 0; st < 4; st++)
#pragma unroll
            for (int i = 0; i < 4; i++) {
                float v = sc[st][i] * scale;
                ps_[st][i] = v;
                tmax = fmaxf(tmax, v);
            }
        tmax = fmaxf(tmax, __shfl_xor(tmax, 16, 64));
        tmax = fmaxf(tmax, __shfl_xor(tmax, 32, 64));
        float mn = fmaxf(m, tmax);
        float cq = __expf(m - mn);
        m = mn;
        float rs = 0.f;
#pragma unroll
        for (int st = 0; st < 4; st++)
#pragma unroll
            for (int i = 0; i < 4; i++) {
                float e = __expf(ps_[st][i] - mn);
                ps_[st][i] = e;
                rs += e;
            }
        rs += __shfl_xor(rs, 16, 64);
        rs += __shfl_xor(rs, 32, 64);
        l = l * cq + rs;

#pragma unroll
        for (int i = 0; i < 4; i++) {
            float ci = __shfl(cq, (lane & 48) | (lk * 4 + i), 64);
#pragma unroll
            for (int dst = 0; dst < 4; dst++) od[dst][i] *= ci;
        }

        unsigned int pd0 = pack2bf(ps_[0][0], ps_[0][1]);
        unsigned int pd1 = pack2bf(ps_[0][2], ps_[0][3]);
        unsigned int pd2 = pack2bf(ps_[1][0], ps_[1][1]);
        unsigned int pd3 = pack2bf(ps_[1][2], ps_[1][3]);
        unsigned int pd4 = pack2bf(ps_[2][0], ps_[2][1]);
        unsigned int pd5 = pack2bf(ps_[2][2], ps_[2][3]);
        unsigned int pd6 = pack2bf(ps_[3][0], ps_[3][1]);
        unsigned int pd7 = pack2bf(ps_[3][2], ps_[3][3]);

        int s0 = __shfl((int)pd0, sA, 64), s2 = __shfl((int)pd2, sA, 64);
        int s1 = __shfl((int)pd1, sA, 64), s3 = __shfl((int)pd3, sA, 64);
        int u0 = __shfl((int)pd0, sB, 64), u2 = __shfl((int)pd2, sB, 64);
        int u1 = __shfl((int)pd1, sB, 64), u3 = __shfl((int)pd3, sB, 64);
        int T00 = hi ? s2 : s0, T01 = hi ? s3 : s1;
        int T02 = hi ? u2 : u0, T03 = hi ? u3 : u1;
        int s4 = __shfl((int)pd4, sA, 64), s6 = __shfl((int)pd6, sA, 64);
        int s5 = __shfl((int)pd5, sA, 64), s7 = __shfl((int)pd7, sA, 64);
        int u4 = __shfl((int)pd4, sB, 64), u6 = __shfl((int)pd6, sB, 64);
        int u5 = __shfl((int)pd5, sB, 64), u7 = __shfl((int)pd7, sB, 64);
        int T10 = hi ? s6 : s4, T11 = hi ? s7 : s5;
        int T12 = hi ? u6 : u4, T13 = hi ? u7 : u5;

        int4 w0 = {T00, T01, T02, T03};
        int4 w1 = {T10, T11, T12, T13};
        s8v pf0 = __builtin_bit_cast(s8v, w0);
        s8v pf1 = __builtin_bit_cast(s8v, w1);

#pragma unroll
        for (int dst = 0; dst < 4; dst++) {
            s8v vf0 = *(const s8v*)&Vt[dst * 16 + lr][lk * 8];
            s8v vf1 = *(const s8v*)&Vt[dst * 16 + lr][32 + lk * 8];
            od[dst] = __builtin_amdgcn_mfma_f32_16x16x32_bf16(pf0, vf0, od[dst], 0, 0, 0);
            od[dst] = __builtin_amdgcn_mfma_f32_16x16x32_bf16(pf1, vf1, od[dst], 0, 0, 0);
        }
    }

    const long pb = ((long)(kh * 16 + bh)) * S;
    if (lk == 0) {
        int q = qt * 64 + w * 16 + lr;
        ML[(pb + q) * 2 + 0] = m;
        ML[(pb + q) * 2 + 1] = l;
    }
#pragma unroll
    for (int dst = 0; dst < 4; dst++)
#pragma unroll
        for (int i = 0; i < 4; i++) {
            int q = qt * 64 + w * 16 + lk * 4 + i;
            int d = dst * 16 + lr;
            Opart[(pb + q) * HD + d] = od[dst][i];
        }
}

// ---------------------------------------------------------------------------
// Combine the two key-half partials -> bf16 ctx (B,S,D).
// ---------------------------------------------------------------------------
__global__ __launch_bounds__(256) void attn_combine(
    const float* __restrict__ Opart, const float* __restrict__ ML,
    short* __restrict__ ctxb)
{
    long idx = (long)blockIdx.x * 256 + threadIdx.x;
    long f = idx * 4;
    int d = (int)(f & 63);
    long x = f >> 6;
    int bh = (int)(x / S);
    int q = (int)(x - (long)bh * S);
    long x1 = x + (long)16 * S;
    float m0 = ML[x * 2], l0 = ML[x * 2 + 1];
    float m1 = ML[x1 * 2], l1 = ML[x1 * 2 + 1];
    float mm = fmaxf(m0, m1);
    float e0 = __expf(m0 - mm), e1 = __expf(m1 - mm);
    float inv = 1.f / (l0 * e0 + l1 * e1);
    float4 o0 = *(const float4*)&Opart[x * HD + d];
    float4 o1 = *(const float4*)&Opart[x1 * HD + d];
    int b = bh >> 3, h = bh & 7;
    short4 r;
    r.x = f2bf((o0.x * e0 + o1.x * e1) * inv);
    r.y = f2bf((o0.y * e0 + o1.y * e1) * inv);
    r.z = f2bf((o0.z * e0 + o1.z * e1) * inv);
    r.w = f2bf((o0.w * e0 + o1.w * e1) * inv);
    *(short4*)&ctxb[((long)(b * S + q)) * D + h * HD + d] = r;
}

// ---------------------------------------------------------------------------
// LayerNorm: out = LN(a + r) * g + be; optional bf16 copy.
// ---------------------------------------------------------------------------
template<int WB>
__global__ __launch_bounds__(256) void ln_kernel(
    const float* __restrict__ a, const float* __restrict__ r,
    const float* __restrict__ g, const float* __restrict__ be,
    float* __restrict__ out, short* __restrict__ outb)
{
    const long row = blockIdx.x;
    const int t = threadIdx.x;
    const float* pa = a + row * D;
    const float* pr = r + row * D;
    float v0 = pa[t] + pr[t];
    float v1 = pa[t + 256] + pr[t + 256];
    float s1 = v0 + v1, s2 = v0 * v0 + v1 * v1;
    for (int off = 32; off; off >>= 1) {
        s1 += __shfl_xor(s1, off, 64);
        s2 += __shfl_xor(s2, off, 64);
    }
    __shared__ float red[8];
    int w = t >> 6, lane = t & 63;
    if (lane == 0) { red[w] = s1; red[4 + w] = s2; }
    __syncthreads();
    float sum = red[0] + red[1] + red[2] + red[3];
    float ssq = red[4] + red[5] + red[6] + red[7];
    float mean = sum * (1.f / D);
    float var = ssq * (1.f / D) - mean * mean;
    float rstd = rsqrtf(var + EPS);
    float r0 = (v0 - mean) * rstd * g[t] + be[t];
    float r1 = (v1 - mean) * rstd * g[t + 256] + be[t + 256];
    out[row * D + t] = r0;
    out[row * D + t + 256] = r1;
    if (WB) {
        outb[row * D + t] = f2bf(r0);
        outb[row * D + t + 256] = f2bf(r1);
    }
}

// ---------------------------------------------------------------------------
extern "C" void kernel_launch(void* const* d_in, const int* in_sizes, int n_in,
                              void* d_out, int out_size, void* d_ws, size_t ws_size,
                              hipStream_t stream)
{
    const float* src      = (const float*)d_in[0];
    const int*   rec_idx  = (const int*)d_in[1];
    const int*   cac_idx  = (const int*)d_in[2];
    const float* k_cached = (const float*)d_in[3];
    const float* v_cached = (const float*)d_in[4];
    const float* in_w     = (const float*)d_in[5];
    const float* in_b     = (const float*)d_in[6];
    const float* out_w    = (const float*)d_in[7];
    const float* out_b    = (const float*)d_in[8];
    const float* w1       = (const float*)d_in[9];
    const float* b1       = (const float*)d_in[10];
    const float* w2       = (const float*)d_in[11];
    const float* b2       = (const float*)d_in[12];
    const float* n1w      = (const float*)d_in[13];
    const float* n1b      = (const float*)d_in[14];
    const float* n2w      = (const float*)d_in[15];
    const float* n2b      = (const float*)d_in[16];

    // ---- workspace layout (shorts first, then floats) ----
    short* SRCb = (short*)d_ws;              // 3145728
    short* WIb  = SRCb + 3145728;            // 786432  (in_proj 3D x D)
    short* WOb  = WIb  + 786432;             // 262144
    short* W1b  = WOb  + 262144;             // 1048576
    short* W2b  = W1b  + 1048576;            // 1048576
    short* Qb   = W2b  + 1048576;            // 3145728
    short* KF   = Qb   + 3145728;            // 3145728
    short* VT   = KF   + 3145728;            // 3145728 (V^T [b,h,hd,s])
    short* CTXb = VT   + 3145728;            // 3145728
    short* Xb   = CTXb + 3145728;            // 3145728
    short* HIDb = Xb   + 3145728;            // 12582912 (FFN hidden bf16)
    float* Opart = (float*)HIDb;             // alias: 6291456 f, dead pre-FFN1
    float* AO   = (float*)(HIDb + 12582912); // 3145728 f
    float* X    = AO + 3145728;              // 3145728 f
    float* ML   = X  + 3145728;              // 196608 f
    float* out  = (float*)d_out;

    dim3 blk(256);

    // 0. one-time bf16 conversions
    f2b_kernel<<<dim3(B * S * D / 1024), blk, 0, stream>>>(src, SRCb, B * S * D);
    f2b_kernel<<<dim3(3 * D * D / 1024), blk, 0, stream>>>(in_w, WIb, 3 * D * D);
    f2b_kernel<<<dim3(D * D / 1024), blk, 0, stream>>>(out_w, WOb, D * D);
    f2b_kernel<<<dim3(DFF * D / 1024), blk, 0, stream>>>(w1, W1b, DFF * D);
    f2b_kernel<<<dim3(D * DFF / 1024), blk, 0, stream>>>(w2, W2b, D * DFF);

    // 1. Q projection -> bf16 (B,H,S,HD)
    gemm128<1, 0, 0><<<dim3(D / 128, (B * S) / 128), blk, 0, stream>>>(
        SRCb, WIb, in_b, Qb, nullptr, B * S, D, D, rec_idx);
    // 2. K/V projection of recomputed rows -> K_full / V^T
    gemm128<2, 0, 0><<<dim3((2 * D) / 128, (B * R) / 128), blk, 0, stream>>>(
        SRCb, WIb + D * D, in_b + D, KF, VT, B * R, 2 * D, D, rec_idx);
    // 3. scatter cached K (row-major) and V (transposed)
    scatter_cached_k<<<dim3((H * SC * HD + 255) / 256), blk, 0, stream>>>(
        k_cached, cac_idx, KF);
    scatter_cached_vT<<<dim3(SC / 64, H), blk, 0, stream>>>(
        v_cached, cac_idx, VT);
    // 4. split-K flash attention + combine -> bf16 CTX
    attn_mfma<<<dim3(B * H * (S / 64), 2), blk, 0, stream>>>(
        Qb, KF, VT, Opart, ML);
    attn_combine<<<dim3((B * H * S * HD / 4) / 256), blk, 0, stream>>>(
        Opart, ML, CTXb);
    // 5. out projection -> AO fp32
    gemm128<0, 0, 0><<<dim3(D / 128, (B * S) / 128), blk, 0, stream>>>(
        CTXb, WOb, out_b, AO, nullptr, B * S, D, D, nullptr);
    // 6. LN1: X = LN(src + AO), plus bf16 copy Xb
    ln_kernel<1><<<dim3(B * S), blk, 0, stream>>>(src, AO, n1w, n1b, X, Xb);
    // 7. FFN1 + ReLU -> bf16 hidden
    gemm128<0, 1, 1><<<dim3(DFF / 128, (B * S) / 128), blk, 0, stream>>>(
        Xb, W1b, b1, HIDb, nullptr, B * S, DFF, D, nullptr);
    // 8. FFN2 -> AO fp32
    gemm128<0, 0, 0><<<dim3(D / 128, (B * S) / 128), blk, 0, stream>>>(
        HIDb, W2b, b2, AO, nullptr, B * S, D, DFF, nullptr);
    // 9. LN2 -> d_out
    ln_kernel<0><<<dim3(B * S), blk, 0, stream>>>(X, AO, n2w, n2b, out, nullptr);
}